// Round 2
// baseline (1602.008 us; speedup 1.0000x reference)
//
#include <hip/hip_runtime.h>
#include <hip/hip_bf16.h>

#define D_MODEL 768
#define D_INNER 1536
#define N_STATE 16
#define DT_RANK 96
#define KCONV   4
#define Bv      2
#define Lv      1024
#define MROWS   (Bv*Lv)   // 2048

// ---------------- LayerNorm: one block (256 thr) per row of 768 ----------------
__global__ __launch_bounds__(256)
void ln_kernel(const float* __restrict__ u, const float* __restrict__ w,
               const float* __restrict__ bvec, float* __restrict__ o)
{
    int row = blockIdx.x;
    const float* x = u + (size_t)row * D_MODEL;
    int t = threadIdx.x;
    float v0 = x[t], v1 = x[t + 256], v2 = x[t + 512];
    float s  = v0 + v1 + v2;
    float s2 = v0*v0 + v1*v1 + v2*v2;
    for (int off = 32; off; off >>= 1) {
        s  += __shfl_down(s, off);
        s2 += __shfl_down(s2, off);
    }
    __shared__ float rs[4], rs2[4];
    __shared__ float mu_s, rstd_s;
    int wid = t >> 6, lane = t & 63;
    if (lane == 0) { rs[wid] = s; rs2[wid] = s2; }
    __syncthreads();
    if (t == 0) {
        float S  = rs[0] + rs[1] + rs[2] + rs[3];
        float S2 = rs2[0] + rs2[1] + rs2[2] + rs2[3];
        float mu = S / (float)D_MODEL;
        float var = S2 / (float)D_MODEL - mu * mu;
        mu_s = mu;
        rstd_s = rsqrtf(var + 1e-5f);
    }
    __syncthreads();
    float mu = mu_s, r = rstd_s;
    float* orow = o + (size_t)row * D_MODEL;
    orow[t]       = (v0 - mu) * r * w[t]       + bvec[t];
    orow[t + 256] = (v1 - mu) * r * w[t + 256] + bvec[t + 256];
    orow[t + 512] = (v2 - mu) * r * w[t + 512] + bvec[t + 512];
}

// ---------------- Generic fp32 GEMM: C[M,N] = A[M,K(+off)] * W[N,K]^T ----------------
// BM=BN=64, BK=16, 256 threads, 4x4 micro-tile per thread.
// revA: logical row m=b*L+l reads physical row b*L+(L-1-l).
// act: 0=none, 2=softplus(+bias). res: optional residual added pre-store.
__global__ __launch_bounds__(256)
void gemm_bt(const float* __restrict__ A, int lda, int aoff, int revA, int Lr,
             const float* __restrict__ W, int ldw,
             const float* __restrict__ bias, int act,
             const float* __restrict__ res, int ldres,
             float* __restrict__ C, int ldc,
             int M, int N, int K)
{
    __shared__ float As[16][64];
    __shared__ float Ws[16][64];
    const int t  = threadIdx.x;
    const int m0 = blockIdx.y * 64, n0 = blockIdx.x * 64;
    const int lr = t >> 2, kq = t & 3;
    int am = m0 + lr;
    if (revA) { int b = am / Lr, l = am % Lr; am = b * Lr + (Lr - 1 - l); }
    const float* Ap = A + (size_t)am * lda + aoff + kq * 4;
    const float* Wp = W + (size_t)(n0 + lr) * ldw + kq * 4;
    const int ty = t >> 4, tx = t & 15;
    float acc[4][4] = {};
    for (int k0 = 0; k0 < K; k0 += 16) {
        float4 av = *(const float4*)(Ap + k0);
        float4 wv = *(const float4*)(Wp + k0);
        __syncthreads();
        As[kq*4+0][lr] = av.x; As[kq*4+1][lr] = av.y;
        As[kq*4+2][lr] = av.z; As[kq*4+3][lr] = av.w;
        Ws[kq*4+0][lr] = wv.x; Ws[kq*4+1][lr] = wv.y;
        Ws[kq*4+2][lr] = wv.z; Ws[kq*4+3][lr] = wv.w;
        __syncthreads();
        #pragma unroll
        for (int k = 0; k < 16; k++) {
            float4 ra = *(const float4*)&As[k][ty << 2];
            float4 rw = *(const float4*)&Ws[k][tx << 2];
            float a4[4] = {ra.x, ra.y, ra.z, ra.w};
            float w4[4] = {rw.x, rw.y, rw.z, rw.w};
            #pragma unroll
            for (int i = 0; i < 4; i++)
                #pragma unroll
                for (int j = 0; j < 4; j++)
                    acc[i][j] = fmaf(a4[i], w4[j], acc[i][j]);
        }
    }
    #pragma unroll
    for (int i = 0; i < 4; i++) {
        int row = m0 + (ty << 2) + i;
        #pragma unroll
        for (int j = 0; j < 4; j++) {
            int col = n0 + (tx << 2) + j;
            float v = acc[i][j];
            if (bias) v += bias[col];
            if (act == 2) v = (v > 20.f) ? v : log1pf(__expf(v));
            if (res)  v += res[(size_t)row * ldres + col];
            C[(size_t)row * ldc + col] = v;
        }
    }
}

// ---------------- Causal depthwise conv (K=4) + SiLU ----------------
// src = x-half of xz (cols 0..1535 of 3072-wide); dst = x buffer (1536-wide).
// One thread handles 8 consecutive l for a fixed (b,d).
__global__ __launch_bounds__(256)
void conv_silu(const float* __restrict__ xz, const float* __restrict__ w,
               const float* __restrict__ bias, float* __restrict__ xo)
{
    int t  = blockIdx.x * 256 + threadIdx.x;
    int d  = t % D_INNER;
    int lc = (t / D_INNER) % (Lv / 8);
    int b  = t / (D_INNER * (Lv / 8));
    int l0 = lc * 8;
    const float* src = xz + (size_t)b * Lv * (2 * D_INNER) + d;
    float w0 = w[d*4], w1 = w[d*4+1], w2 = w[d*4+2], w3 = w[d*4+3];
    float bb = bias[d];
    float v[11];
    #pragma unroll
    for (int j = 0; j < 11; j++) {
        int l = l0 - 3 + j;
        v[j] = (l >= 0) ? src[(size_t)l * (2 * D_INNER)] : 0.f;
    }
    float* dst = xo + ((size_t)b * Lv + l0) * D_INNER + d;
    #pragma unroll
    for (int j = 0; j < 8; j++) {
        float a = bb + w0*v[j] + w1*v[j+1] + w2*v[j+2] + w3*v[j+3];
        a = a / (1.f + __expf(-a));  // SiLU
        dst[(size_t)j * D_INNER] = a;
    }
}

// ---------------- Selective scan + gate ----------------
// One lane per (b,d,n); 16-lane butterfly reduces sum_n h*C.
// grid.y selects branch (0=fwd, 1=bwd). bwd buffers are in reversed-time
// layout; output write un-reverses.
__global__ __launch_bounds__(256)
void scan_kernel(const float* __restrict__ xF,  const float* __restrict__ dtF,
                 const float* __restrict__ xdF, const float* __restrict__ xzF,
                 const float* __restrict__ AlF, const float* __restrict__ DFp,
                 const float* __restrict__ xB,  const float* __restrict__ dtB,
                 const float* __restrict__ xdB, const float* __restrict__ xzB,
                 const float* __restrict__ AlB, const float* __restrict__ DBp,
                 float* __restrict__ ycat)
{
    const int br = blockIdx.y;
    const float* x    = br ? xB  : xF;
    const float* dt   = br ? dtB : dtF;
    const float* xd   = br ? xdB : xdF;
    const float* xz   = br ? xzB : xzF;
    const float* Alog = br ? AlB : AlF;
    const float* Dp   = br ? DBp : DFp;

    int t = blockIdx.x * 256 + threadIdx.x;
    int n = t & 15;
    int d = (t >> 4) % D_INNER;
    int b = t / (16 * D_INNER);

    float An = -__expf(Alog[d * N_STATE + n]);
    float Dd = Dp[d];
    float h = 0.f;

    const float* xrow  = x  + (size_t)b * Lv * D_INNER + d;
    const float* dtrow = dt + (size_t)b * Lv * D_INNER + d;
    const float* zrow  = xz + (size_t)b * Lv * (2 * D_INNER) + D_INNER + d;
    const float* xdr   = xd + (size_t)b * Lv * 128;

    for (int l = 0; l < Lv; l++) {
        float dtl  = dtrow[(size_t)l * D_INNER];
        float xl   = xrow[(size_t)l * D_INNER];
        float bsel = xdr[(size_t)l * 128 + DT_RANK + n];
        float csel = xdr[(size_t)l * 128 + DT_RANK + N_STATE + n];
        float ab = __expf(dtl * An);
        h = fmaf(ab, h, dtl * xl * bsel);
        float contrib = h * csel;
        contrib += __shfl_xor(contrib, 1);
        contrib += __shfl_xor(contrib, 2);
        contrib += __shfl_xor(contrib, 4);
        contrib += __shfl_xor(contrib, 8);
        if (n == 0) {
            float y = contrib + xl * Dd;
            float zl = zrow[(size_t)l * (2 * D_INNER)];
            y *= zl / (1.f + __expf(-zl));     // * silu(z)
            int lo = br ? (Lv - 1 - l) : l;
            ycat[((size_t)b * Lv + lo) * (2 * D_INNER) + br * D_INNER + d] = y;
        }
    }
}

extern "C" void kernel_launch(void* const* d_in, const int* in_sizes, int n_in,
                              void* d_out, int out_size, void* d_ws, size_t ws_size,
                              hipStream_t stream)
{
    (void)in_sizes; (void)n_in; (void)out_size; (void)ws_size;
    const float* u        = (const float*)d_in[0];
    const float* norm_w   = (const float*)d_in[1];
    const float* norm_b   = (const float*)d_in[2];
    const float* f_in_w   = (const float*)d_in[3];
    const float* f_conv_w = (const float*)d_in[4];
    const float* f_conv_b = (const float*)d_in[5];
    const float* f_Alog   = (const float*)d_in[6];
    const float* f_xproj  = (const float*)d_in[7];
    const float* f_dt_w   = (const float*)d_in[8];
    const float* f_dt_b   = (const float*)d_in[9];
    const float* f_D      = (const float*)d_in[10];
    const float* b_in_w   = (const float*)d_in[11];
    const float* b_conv_w = (const float*)d_in[12];
    const float* b_conv_b = (const float*)d_in[13];
    const float* b_Alog   = (const float*)d_in[14];
    const float* b_xproj  = (const float*)d_in[15];
    const float* b_dt_w   = (const float*)d_in[16];
    const float* b_dt_b   = (const float*)d_in[17];
    const float* b_D      = (const float*)d_in[18];
    const float* out_w    = (const float*)d_in[19];
    float* out = (float*)d_out;

    float* ws = (float*)d_ws;
    float* un     = ws;                          // 2048*768
    float* xz_f   = un     + (size_t)MROWS * D_MODEL;        // 2048*3072
    float* xz_b   = xz_f   + (size_t)MROWS * 2 * D_INNER;
    float* x_f    = xz_b   + (size_t)MROWS * 2 * D_INNER;    // 2048*1536
    float* x_b    = x_f    + (size_t)MROWS * D_INNER;
    float* xdbl_f = x_b    + (size_t)MROWS * D_INNER;        // 2048*128
    float* xdbl_b = xdbl_f + (size_t)MROWS * 128;
    float* dt_f   = xdbl_b + (size_t)MROWS * 128;            // 2048*1536
    float* dt_b_  = dt_f   + (size_t)MROWS * D_INNER;
    float* ycat   = dt_b_  + (size_t)MROWS * D_INNER;        // 2048*3072

    // 1. LayerNorm
    ln_kernel<<<MROWS, 256, 0, stream>>>(u, norm_w, norm_b, un);

    // 2. in-proj GEMMs (bwd reads reversed rows)
    gemm_bt<<<dim3(2*D_INNER/64, MROWS/64), 256, 0, stream>>>(
        un, D_MODEL, 0, 0, Lv, f_in_w, D_MODEL, nullptr, 0, nullptr, 0,
        xz_f, 2*D_INNER, MROWS, 2*D_INNER, D_MODEL);
    gemm_bt<<<dim3(2*D_INNER/64, MROWS/64), 256, 0, stream>>>(
        un, D_MODEL, 0, 1, Lv, b_in_w, D_MODEL, nullptr, 0, nullptr, 0,
        xz_b, 2*D_INNER, MROWS, 2*D_INNER, D_MODEL);

    // 3. conv + SiLU
    int convBlocks = (Bv * (Lv/8) * D_INNER) / 256;
    conv_silu<<<convBlocks, 256, 0, stream>>>(xz_f, f_conv_w, f_conv_b, x_f);
    conv_silu<<<convBlocks, 256, 0, stream>>>(xz_b, b_conv_w, b_conv_b, x_b);

    // 4. x-proj GEMMs (N=128)
    gemm_bt<<<dim3(128/64, MROWS/64), 256, 0, stream>>>(
        x_f, D_INNER, 0, 0, Lv, f_xproj, D_INNER, nullptr, 0, nullptr, 0,
        xdbl_f, 128, MROWS, 128, D_INNER);
    gemm_bt<<<dim3(128/64, MROWS/64), 256, 0, stream>>>(
        x_b, D_INNER, 0, 0, Lv, b_xproj, D_INNER, nullptr, 0, nullptr, 0,
        xdbl_b, 128, MROWS, 128, D_INNER);

    // 5. dt GEMMs + bias + softplus (K=96 slice of xdbl)
    gemm_bt<<<dim3(D_INNER/64, MROWS/64), 256, 0, stream>>>(
        xdbl_f, 128, 0, 0, Lv, f_dt_w, DT_RANK, f_dt_b, 2, nullptr, 0,
        dt_f, D_INNER, MROWS, D_INNER, DT_RANK);
    gemm_bt<<<dim3(D_INNER/64, MROWS/64), 256, 0, stream>>>(
        xdbl_b, 128, 0, 0, Lv, b_dt_w, DT_RANK, b_dt_b, 2, nullptr, 0,
        dt_b_, D_INNER, MROWS, D_INNER, DT_RANK);

    // 6. selective scan + gate, both branches
    scan_kernel<<<dim3((Bv * D_INNER * 16) / 256, 2), 256, 0, stream>>>(
        x_f, dt_f, xdbl_f, xz_f, f_Alog, f_D,
        x_b, dt_b_, xdbl_b, xz_b, b_Alog, b_D, ycat);

    // 7. out-proj GEMM + residual
    gemm_bt<<<dim3(D_MODEL/64, MROWS/64), 256, 0, stream>>>(
        ycat, 2*D_INNER, 0, 0, Lv, out_w, 2*D_INNER, nullptr, 0, u, D_MODEL,
        out, D_MODEL, MROWS, D_MODEL, 2*D_INNER);
}

// Round 3
// 1157.441 us; speedup vs baseline: 1.3841x; 1.3841x over previous
//
#include <hip/hip_runtime.h>
#include <hip/hip_bf16.h>

#define D_MODEL 768
#define D_INNER 1536
#define N_STATE 16
#define DT_RANK 96
#define KCONV   4
#define Bv      2
#define Lv      1024
#define MROWS   (Bv*Lv)   // 2048

// ---------------- LayerNorm: one block (256 thr) per row of 768 ----------------
__global__ __launch_bounds__(256)
void ln_kernel(const float* __restrict__ u, const float* __restrict__ w,
               const float* __restrict__ bvec, float* __restrict__ o)
{
    int row = blockIdx.x;
    const float* x = u + (size_t)row * D_MODEL;
    int t = threadIdx.x;
    float v0 = x[t], v1 = x[t + 256], v2 = x[t + 512];
    float s  = v0 + v1 + v2;
    float s2 = v0*v0 + v1*v1 + v2*v2;
    for (int off = 32; off; off >>= 1) {
        s  += __shfl_down(s, off);
        s2 += __shfl_down(s2, off);
    }
    __shared__ float rs[4], rs2[4];
    __shared__ float mu_s, rstd_s;
    int wid = t >> 6, lane = t & 63;
    if (lane == 0) { rs[wid] = s; rs2[wid] = s2; }
    __syncthreads();
    if (t == 0) {
        float S  = rs[0] + rs[1] + rs[2] + rs[3];
        float S2 = rs2[0] + rs2[1] + rs2[2] + rs2[3];
        float mu = S / (float)D_MODEL;
        float var = S2 / (float)D_MODEL - mu * mu;
        mu_s = mu;
        rstd_s = rsqrtf(var + 1e-5f);
    }
    __syncthreads();
    float mu = mu_s, r = rstd_s;
    float* orow = o + (size_t)row * D_MODEL;
    orow[t]       = (v0 - mu) * r * w[t]       + bvec[t];
    orow[t + 256] = (v1 - mu) * r * w[t + 256] + bvec[t + 256];
    orow[t + 512] = (v2 - mu) * r * w[t + 512] + bvec[t + 512];
}

// ---------------- Generic fp32 GEMM: C[M,N] = A[M,K(+off)] * W[N,K]^T ----------------
__global__ __launch_bounds__(256)
void gemm_bt(const float* __restrict__ A, int lda, int aoff, int revA, int Lr,
             const float* __restrict__ W, int ldw,
             const float* __restrict__ bias, int act,
             const float* __restrict__ res, int ldres,
             float* __restrict__ C, int ldc,
             int M, int N, int K)
{
    __shared__ float As[16][64];
    __shared__ float Ws[16][64];
    const int t  = threadIdx.x;
    const int m0 = blockIdx.y * 64, n0 = blockIdx.x * 64;
    const int lr = t >> 2, kq = t & 3;
    int am = m0 + lr;
    if (revA) { int b = am / Lr, l = am % Lr; am = b * Lr + (Lr - 1 - l); }
    const float* Ap = A + (size_t)am * lda + aoff + kq * 4;
    const float* Wp = W + (size_t)(n0 + lr) * ldw + kq * 4;
    const int ty = t >> 4, tx = t & 15;
    float acc[4][4] = {};
    for (int k0 = 0; k0 < K; k0 += 16) {
        float4 av = *(const float4*)(Ap + k0);
        float4 wv = *(const float4*)(Wp + k0);
        __syncthreads();
        As[kq*4+0][lr] = av.x; As[kq*4+1][lr] = av.y;
        As[kq*4+2][lr] = av.z; As[kq*4+3][lr] = av.w;
        Ws[kq*4+0][lr] = wv.x; Ws[kq*4+1][lr] = wv.y;
        Ws[kq*4+2][lr] = wv.z; Ws[kq*4+3][lr] = wv.w;
        __syncthreads();
        #pragma unroll
        for (int k = 0; k < 16; k++) {
            float4 ra = *(const float4*)&As[k][ty << 2];
            float4 rw = *(const float4*)&Ws[k][tx << 2];
            float a4[4] = {ra.x, ra.y, ra.z, ra.w};
            float w4[4] = {rw.x, rw.y, rw.z, rw.w};
            #pragma unroll
            for (int i = 0; i < 4; i++)
                #pragma unroll
                for (int j = 0; j < 4; j++)
                    acc[i][j] = fmaf(a4[i], w4[j], acc[i][j]);
        }
    }
    #pragma unroll
    for (int i = 0; i < 4; i++) {
        int row = m0 + (ty << 2) + i;
        #pragma unroll
        for (int j = 0; j < 4; j++) {
            int col = n0 + (tx << 2) + j;
            float v = acc[i][j];
            if (bias) v += bias[col];
            if (act == 2) v = (v > 20.f) ? v : log1pf(__expf(v));
            if (res)  v += res[(size_t)row * ldres + col];
            C[(size_t)row * ldc + col] = v;
        }
    }
}

// ---------------- Causal depthwise conv (K=4) + SiLU ----------------
__global__ __launch_bounds__(256)
void conv_silu(const float* __restrict__ xz, const float* __restrict__ w,
               const float* __restrict__ bias, float* __restrict__ xo)
{
    int t  = blockIdx.x * 256 + threadIdx.x;
    int d  = t % D_INNER;
    int lc = (t / D_INNER) % (Lv / 8);
    int b  = t / (D_INNER * (Lv / 8));
    int l0 = lc * 8;
    const float* src = xz + (size_t)b * Lv * (2 * D_INNER) + d;
    float w0 = w[d*4], w1 = w[d*4+1], w2 = w[d*4+2], w3 = w[d*4+3];
    float bb = bias[d];
    float v[11];
    #pragma unroll
    for (int j = 0; j < 11; j++) {
        int l = l0 - 3 + j;
        v[j] = (l >= 0) ? src[(size_t)l * (2 * D_INNER)] : 0.f;
    }
    float* dst = xo + ((size_t)b * Lv + l0) * D_INNER + d;
    #pragma unroll
    for (int j = 0; j < 8; j++) {
        float a = bb + w0*v[j] + w1*v[j+1] + w2*v[j+2] + w3*v[j+3];
        a = a / (1.f + __expf(-a));  // SiLU
        dst[(size_t)j * D_INNER] = a;
    }
}

// ---------------- Selective scan + gate (LDS-staged, double-buffered) ----------------
// Block = 128 threads: 8 d-values x 16 n-states, one (branch, batch) per block.z/y.
// L processed in 16 chunks of 64; x/dt/z/B/C staged via global_load_lds (16B),
// double-buffered; compute reads LDS (broadcast-friendly, conflict-free).
#define SCH 64           // timesteps per chunk
#define SNC (Lv/SCH)     // 16 chunks

__device__ __forceinline__ void gll16(const float* g, float* l) {
    __builtin_amdgcn_global_load_lds(
        (const __attribute__((address_space(1))) void*)g,
        (__attribute__((address_space(3))) void*)l, 16, 0, 0);
}

__global__ __launch_bounds__(128)
void scan_kernel(const float* __restrict__ xF,  const float* __restrict__ dtF,
                 const float* __restrict__ xdF, const float* __restrict__ xzF,
                 const float* __restrict__ AlF, const float* __restrict__ DFp,
                 const float* __restrict__ xB,  const float* __restrict__ dtB,
                 const float* __restrict__ xdB, const float* __restrict__ xzB,
                 const float* __restrict__ AlB, const float* __restrict__ DBp,
                 float* __restrict__ ycat)
{
    const int br = blockIdx.z;
    const int bb = blockIdx.y;
    const int d0 = blockIdx.x * 8;

    const float* x    = br ? xB  : xF;
    const float* dt   = br ? dtB : dtF;
    const float* xd   = br ? xdB : xdF;
    const float* xz   = br ? xzB : xzF;
    const float* Alog = br ? AlB : AlF;
    const float* Dp   = br ? DBp : DFp;

    __shared__ float xs [2][SCH][8];
    __shared__ float dts[2][SCH][8];
    __shared__ float zs [2][SCH][8];
    __shared__ float Bs [2][SCH][16];
    __shared__ float Cs [2][SCH][16];

    const int t = threadIdx.x;
    const int n = t & 15, dloc = t >> 4;

    // base pointers for this (br, b)
    const float* xg  = x  + (size_t)bb * Lv * D_INNER + d0;
    const float* dtg = dt + (size_t)bb * Lv * D_INNER + d0;
    const float* zg  = xz + (size_t)bb * Lv * (2*D_INNER) + D_INNER + d0;
    const float* bcg = xd + (size_t)bb * Lv * 128;

    // staging indices: x/dt/z: li = t>>1 (64 rows), dq = t&1 (2 float4 per row)
    const int sli = t >> 1, sdq = (t & 1) * 4;
    // B/C: two slots s = t, t+128; li = s>>2, q = (s&3)*4
    const int bl0 = t >> 2,        bq0 = (t & 3) * 4;
    const int bl1 = (t + 128) >> 2, bq1 = ((t + 128) & 3) * 4;

    #define STAGE(c, p) do {                                                     \
        int l0_ = (c) * SCH;                                                     \
        gll16(xg  + (size_t)(l0_ + sli) * D_INNER     + sdq, &xs [p][sli][sdq]); \
        gll16(dtg + (size_t)(l0_ + sli) * D_INNER     + sdq, &dts[p][sli][sdq]); \
        gll16(zg  + (size_t)(l0_ + sli) * (2*D_INNER) + sdq, &zs [p][sli][sdq]); \
        gll16(bcg + (size_t)(l0_ + bl0) * 128 + DT_RANK           + bq0, &Bs[p][bl0][bq0]); \
        gll16(bcg + (size_t)(l0_ + bl1) * 128 + DT_RANK           + bq1, &Bs[p][bl1][bq1]); \
        gll16(bcg + (size_t)(l0_ + bl0) * 128 + DT_RANK + N_STATE + bq0, &Cs[p][bl0][bq0]); \
        gll16(bcg + (size_t)(l0_ + bl1) * 128 + DT_RANK + N_STATE + bq1, &Cs[p][bl1][bq1]); \
    } while (0)

    const float An = -__expf(Alog[(d0 + dloc) * N_STATE + n]);
    const float Dd = Dp[d0 + dloc];
    float h = 0.f;

    float* yout = ycat + br * D_INNER + d0 + dloc;

    STAGE(0, 0);
    __syncthreads();

    for (int c = 0; c < SNC; ++c) {
        const int p = c & 1;
        if (c + 1 < SNC) STAGE(c + 1, p ^ 1);

        #pragma unroll 4
        for (int l = 0; l < SCH; ++l) {
            float dtl  = dts[p][l][dloc];
            float xl   = xs [p][l][dloc];
            float bsel = Bs [p][l][n];
            float csel = Cs [p][l][n];
            float ab = __expf(dtl * An);
            h = fmaf(ab, h, dtl * xl * bsel);
            float contrib = h * csel;
            contrib += __shfl_xor(contrib, 1);
            contrib += __shfl_xor(contrib, 2);
            contrib += __shfl_xor(contrib, 4);
            contrib += __shfl_xor(contrib, 8);
            if (n == 0) {
                float zl = zs[p][l][dloc];
                float y = contrib + xl * Dd;
                y *= zl / (1.f + __expf(-zl));   // * silu(z)
                int gl = c * SCH + l;
                int lo = br ? (Lv - 1 - gl) : gl;
                yout[((size_t)bb * Lv + lo) * (2*D_INNER)] = y;
            }
        }
        __syncthreads();
    }
    #undef STAGE
}

extern "C" void kernel_launch(void* const* d_in, const int* in_sizes, int n_in,
                              void* d_out, int out_size, void* d_ws, size_t ws_size,
                              hipStream_t stream)
{
    (void)in_sizes; (void)n_in; (void)out_size; (void)ws_size;
    const float* u        = (const float*)d_in[0];
    const float* norm_w   = (const float*)d_in[1];
    const float* norm_b   = (const float*)d_in[2];
    const float* f_in_w   = (const float*)d_in[3];
    const float* f_conv_w = (const float*)d_in[4];
    const float* f_conv_b = (const float*)d_in[5];
    const float* f_Alog   = (const float*)d_in[6];
    const float* f_xproj  = (const float*)d_in[7];
    const float* f_dt_w   = (const float*)d_in[8];
    const float* f_dt_b   = (const float*)d_in[9];
    const float* f_D      = (const float*)d_in[10];
    const float* b_in_w   = (const float*)d_in[11];
    const float* b_conv_w = (const float*)d_in[12];
    const float* b_conv_b = (const float*)d_in[13];
    const float* b_Alog   = (const float*)d_in[14];
    const float* b_xproj  = (const float*)d_in[15];
    const float* b_dt_w   = (const float*)d_in[16];
    const float* b_dt_b   = (const float*)d_in[17];
    const float* b_D      = (const float*)d_in[18];
    const float* out_w    = (const float*)d_in[19];
    float* out = (float*)d_out;

    float* ws = (float*)d_ws;
    float* un     = ws;                          // 2048*768
    float* xz_f   = un     + (size_t)MROWS * D_MODEL;        // 2048*3072
    float* xz_b   = xz_f   + (size_t)MROWS * 2 * D_INNER;
    float* x_f    = xz_b   + (size_t)MROWS * 2 * D_INNER;    // 2048*1536
    float* x_b    = x_f    + (size_t)MROWS * D_INNER;
    float* xdbl_f = x_b    + (size_t)MROWS * D_INNER;        // 2048*128
    float* xdbl_b = xdbl_f + (size_t)MROWS * 128;
    float* dt_f   = xdbl_b + (size_t)MROWS * 128;            // 2048*1536
    float* dt_b_  = dt_f   + (size_t)MROWS * D_INNER;
    float* ycat   = dt_b_  + (size_t)MROWS * D_INNER;        // 2048*3072

    // 1. LayerNorm
    ln_kernel<<<MROWS, 256, 0, stream>>>(u, norm_w, norm_b, un);

    // 2. in-proj GEMMs (bwd reads reversed rows)
    gemm_bt<<<dim3(2*D_INNER/64, MROWS/64), 256, 0, stream>>>(
        un, D_MODEL, 0, 0, Lv, f_in_w, D_MODEL, nullptr, 0, nullptr, 0,
        xz_f, 2*D_INNER, MROWS, 2*D_INNER, D_MODEL);
    gemm_bt<<<dim3(2*D_INNER/64, MROWS/64), 256, 0, stream>>>(
        un, D_MODEL, 0, 1, Lv, b_in_w, D_MODEL, nullptr, 0, nullptr, 0,
        xz_b, 2*D_INNER, MROWS, 2*D_INNER, D_MODEL);

    // 3. conv + SiLU
    int convBlocks = (Bv * (Lv/8) * D_INNER) / 256;
    conv_silu<<<convBlocks, 256, 0, stream>>>(xz_f, f_conv_w, f_conv_b, x_f);
    conv_silu<<<convBlocks, 256, 0, stream>>>(xz_b, b_conv_w, b_conv_b, x_b);

    // 4. x-proj GEMMs (N=128)
    gemm_bt<<<dim3(128/64, MROWS/64), 256, 0, stream>>>(
        x_f, D_INNER, 0, 0, Lv, f_xproj, D_INNER, nullptr, 0, nullptr, 0,
        xdbl_f, 128, MROWS, 128, D_INNER);
    gemm_bt<<<dim3(128/64, MROWS/64), 256, 0, stream>>>(
        x_b, D_INNER, 0, 0, Lv, b_xproj, D_INNER, nullptr, 0, nullptr, 0,
        xdbl_b, 128, MROWS, 128, D_INNER);

    // 5. dt GEMMs + bias + softplus (K=96 slice of xdbl)
    gemm_bt<<<dim3(D_INNER/64, MROWS/64), 256, 0, stream>>>(
        xdbl_f, 128, 0, 0, Lv, f_dt_w, DT_RANK, f_dt_b, 2, nullptr, 0,
        dt_f, D_INNER, MROWS, D_INNER, DT_RANK);
    gemm_bt<<<dim3(D_INNER/64, MROWS/64), 256, 0, stream>>>(
        xdbl_b, 128, 0, 0, Lv, b_dt_w, DT_RANK, b_dt_b, 2, nullptr, 0,
        dt_b_, D_INNER, MROWS, D_INNER, DT_RANK);

    // 6. selective scan + gate, both branches (768 blocks = 3/CU exactly)
    scan_kernel<<<dim3(D_INNER/8, Bv, 2), 128, 0, stream>>>(
        x_f, dt_f, xdbl_f, xz_f, f_Alog, f_D,
        x_b, dt_b_, xdbl_b, xz_b, b_Alog, b_D, ycat);

    // 7. out-proj GEMM + residual
    gemm_bt<<<dim3(D_MODEL/64, MROWS/64), 256, 0, stream>>>(
        ycat, 2*D_INNER, 0, 0, Lv, out_w, 2*D_INNER, nullptr, 0, u, D_MODEL,
        out, D_MODEL, MROWS, D_MODEL, 2*D_INNER);
}

// Round 4
// 676.240 us; speedup vs baseline: 2.3690x; 1.7116x over previous
//
#include <hip/hip_runtime.h>
#include <hip/hip_bf16.h>

#define D_MODEL 768
#define D_INNER 1536
#define N_STATE 16
#define DT_RANK 96
#define KCONV   4
#define Bv      2
#define Lv      1024
#define MROWS   (Bv*Lv)   // 2048

__device__ __forceinline__ void gll16(const void* g, void* l) {
    __builtin_amdgcn_global_load_lds(
        (const __attribute__((address_space(1))) void*)g,
        (__attribute__((address_space(3))) void*)l, 16, 0, 0);
}

// ---------------- LayerNorm ----------------
__global__ __launch_bounds__(256)
void ln_kernel(const float* __restrict__ u, const float* __restrict__ w,
               const float* __restrict__ bvec, float* __restrict__ o)
{
    int row = blockIdx.x;
    const float* x = u + (size_t)row * D_MODEL;
    int t = threadIdx.x;
    float v0 = x[t], v1 = x[t + 256], v2 = x[t + 512];
    float s  = v0 + v1 + v2;
    float s2 = v0*v0 + v1*v1 + v2*v2;
    for (int off = 32; off; off >>= 1) {
        s  += __shfl_down(s, off);
        s2 += __shfl_down(s2, off);
    }
    __shared__ float rs[4], rs2[4];
    __shared__ float mu_s, rstd_s;
    int wid = t >> 6, lane = t & 63;
    if (lane == 0) { rs[wid] = s; rs2[wid] = s2; }
    __syncthreads();
    if (t == 0) {
        float S  = rs[0] + rs[1] + rs[2] + rs[3];
        float S2 = rs2[0] + rs2[1] + rs2[2] + rs2[3];
        float mu = S / (float)D_MODEL;
        float var = S2 / (float)D_MODEL - mu * mu;
        mu_s = mu;
        rstd_s = rsqrtf(var + 1e-5f);
    }
    __syncthreads();
    float mu = mu_s, r = rstd_s;
    float* orow = o + (size_t)row * D_MODEL;
    orow[t]       = (v0 - mu) * r * w[t]       + bvec[t];
    orow[t + 256] = (v1 - mu) * r * w[t + 256] + bvec[t + 256];
    orow[t + 512] = (v2 - mu) * r * w[t + 512] + bvec[t + 512];
}

// ---------------- fp32 -> bf16 (RNE) ----------------
__device__ __forceinline__ unsigned short f2bf(float f) {
    unsigned u = __builtin_bit_cast(unsigned, f);
    u += 0x7fffu + ((u >> 16) & 1u);
    return (unsigned short)(u >> 16);
}
__global__ __launch_bounds__(256)
void f2b(const float* __restrict__ in, unsigned short* __restrict__ o, int n4)
{
    int i = blockIdx.x * 256 + threadIdx.x;
    if (i < n4) {
        float4 v = ((const float4*)in)[i];
        ushort4 r;
        r.x = f2bf(v.x); r.y = f2bf(v.y); r.z = f2bf(v.z); r.w = f2bf(v.w);
        ((ushort4*)o)[i] = r;
    }
}

// ---------------- bf16 MFMA GEMM: C[M,N](f32) = A[M,K](bf16) * W[N,K]^T(bf16) ----------------
// 128x128 tile, BK=32, 256 thr (4 waves, each 64x64 = 4x4 frags of 16x16x32).
typedef __attribute__((ext_vector_type(8))) short bf16x8;
typedef __attribute__((ext_vector_type(4))) float f32x4;

__global__ __launch_bounds__(256)
void gemm_mfma(const unsigned short* __restrict__ A, int revA, int Lr,
               const unsigned short* __restrict__ W,
               const float* __restrict__ res,
               float* __restrict__ C,
               int M, int N, int K)
{
    __shared__ unsigned short As[128 * 32];
    __shared__ unsigned short Bs[128 * 32];
    const int tid = threadIdx.x;
    const int m0 = blockIdx.y * 128, n0 = blockIdx.x * 128;
    const int lane = tid & 63;
    const int w  = tid >> 6;
    const int wr = w >> 1, wc = w & 1;
    const int lm = lane & 15, lk = lane >> 4;

    // staging: thread -> (row = tid/4, k-chunk = (tid&3)*8), linear LDS dest = tid*16B
    const int srow = tid >> 2;
    const int skq  = (tid & 3) * 8;
    int arow0 = m0 + srow, arow1 = m0 + srow + 64;
    if (revA) {
        arow0 = (arow0 / Lr) * Lr + (Lr - 1 - arow0 % Lr);
        arow1 = (arow1 / Lr) * Lr + (Lr - 1 - arow1 % Lr);
    }
    const unsigned short* a0 = A + (size_t)arow0 * K + skq;
    const unsigned short* a1 = A + (size_t)arow1 * K + skq;
    const unsigned short* w0 = W + (size_t)(n0 + srow) * K + skq;
    const unsigned short* w1 = W + (size_t)(n0 + srow + 64) * K + skq;

    f32x4 acc[4][4] = {};

    for (int k0 = 0; k0 < K; k0 += 32) {
        __syncthreads();
        gll16(a0 + k0, &As[tid * 8]);
        gll16(a1 + k0, &As[2048 + tid * 8]);
        gll16(w0 + k0, &Bs[tid * 8]);
        gll16(w1 + k0, &Bs[2048 + tid * 8]);
        __syncthreads();

        bf16x8 af[4], bfr[4];
        #pragma unroll
        for (int i = 0; i < 4; i++) {
            af[i]  = *(const bf16x8*)&As[(wr * 64 + i * 16 + lm) * 32 + lk * 8];
            bfr[i] = *(const bf16x8*)&Bs[(wc * 64 + i * 16 + lm) * 32 + lk * 8];
        }
        #pragma unroll
        for (int i = 0; i < 4; i++)
            #pragma unroll
            for (int j = 0; j < 4; j++)
                acc[i][j] = __builtin_amdgcn_mfma_f32_16x16x32_bf16(af[i], bfr[j], acc[i][j], 0, 0, 0);
    }

    #pragma unroll
    for (int i = 0; i < 4; i++) {
        #pragma unroll
        for (int j = 0; j < 4; j++) {
            int row = m0 + wr * 64 + i * 16 + lk * 4;
            int col = n0 + wc * 64 + j * 16 + lm;
            #pragma unroll
            for (int r = 0; r < 4; r++) {
                float v = acc[i][j][r];
                if (res) v += res[(size_t)(row + r) * N + col];
                C[(size_t)(row + r) * N + col] = v;
            }
        }
    }
}

// ---------------- Causal depthwise conv (K=4) + SiLU ----------------
__global__ __launch_bounds__(256)
void conv_silu(const float* __restrict__ xz, const float* __restrict__ w,
               const float* __restrict__ bias, float* __restrict__ xo)
{
    int t  = blockIdx.x * 256 + threadIdx.x;
    int d  = t % D_INNER;
    int lc = (t / D_INNER) % (Lv / 8);
    int b  = t / (D_INNER * (Lv / 8));
    int l0 = lc * 8;
    const float* src = xz + (size_t)b * Lv * (2 * D_INNER) + d;
    float w0 = w[d*4], w1 = w[d*4+1], w2 = w[d*4+2], w3 = w[d*4+3];
    float bb = bias[d];
    float v[11];
    #pragma unroll
    for (int j = 0; j < 11; j++) {
        int l = l0 - 3 + j;
        v[j] = (l >= 0) ? src[(size_t)l * (2 * D_INNER)] : 0.f;
    }
    float* dst = xo + ((size_t)b * Lv + l0) * D_INNER + d;
    #pragma unroll
    for (int j = 0; j < 8; j++) {
        float a = bb + w0*v[j] + w1*v[j+1] + w2*v[j+2] + w3*v[j+3];
        a = a / (1.f + __expf(-a));  // SiLU
        dst[(size_t)j * D_INNER] = a;
    }
}

// ---------------- fp32 GEMM (kept for xproj / dt) ----------------
__global__ __launch_bounds__(256)
void gemm_bt(const float* __restrict__ A, int lda, int aoff, int revA, int Lr,
             const float* __restrict__ W, int ldw,
             const float* __restrict__ bias, int act,
             const float* __restrict__ res, int ldres,
             float* __restrict__ C, int ldc,
             int M, int N, int K)
{
    __shared__ float As[16][64];
    __shared__ float Ws[16][64];
    const int t  = threadIdx.x;
    const int m0 = blockIdx.y * 64, n0 = blockIdx.x * 64;
    const int lr = t >> 2, kq = t & 3;
    int am = m0 + lr;
    if (revA) { int b = am / Lr, l = am % Lr; am = b * Lr + (Lr - 1 - l); }
    const float* Ap = A + (size_t)am * lda + aoff + kq * 4;
    const float* Wp = W + (size_t)(n0 + lr) * ldw + kq * 4;
    const int ty = t >> 4, tx = t & 15;
    float acc[4][4] = {};
    for (int k0 = 0; k0 < K; k0 += 16) {
        float4 av = *(const float4*)(Ap + k0);
        float4 wv = *(const float4*)(Wp + k0);
        __syncthreads();
        As[kq*4+0][lr] = av.x; As[kq*4+1][lr] = av.y;
        As[kq*4+2][lr] = av.z; As[kq*4+3][lr] = av.w;
        Ws[kq*4+0][lr] = wv.x; Ws[kq*4+1][lr] = wv.y;
        Ws[kq*4+2][lr] = wv.z; Ws[kq*4+3][lr] = wv.w;
        __syncthreads();
        #pragma unroll
        for (int k = 0; k < 16; k++) {
            float4 ra = *(const float4*)&As[k][ty << 2];
            float4 rw = *(const float4*)&Ws[k][tx << 2];
            float a4[4] = {ra.x, ra.y, ra.z, ra.w};
            float w4[4] = {rw.x, rw.y, rw.z, rw.w};
            #pragma unroll
            for (int i = 0; i < 4; i++)
                #pragma unroll
                for (int j = 0; j < 4; j++)
                    acc[i][j] = fmaf(a4[i], w4[j], acc[i][j]);
        }
    }
    #pragma unroll
    for (int i = 0; i < 4; i++) {
        int row = m0 + (ty << 2) + i;
        #pragma unroll
        for (int j = 0; j < 4; j++) {
            int col = n0 + (tx << 2) + j;
            float v = acc[i][j];
            if (bias) v += bias[col];
            if (act == 2) v = (v > 20.f) ? v : log1pf(__expf(v));
            if (res)  v += res[(size_t)row * ldres + col];
            C[(size_t)row * ldc + col] = v;
        }
    }
}

// ---------------- Selective scan + gate (LDS-staged, DPP reduction) ----------------
#define SCH 64
#define SNC (Lv/SCH)

template<int CTRL>
__device__ __forceinline__ float dpp_ror_add(float v) {
    int vi = __builtin_bit_cast(int, v);
    int mv = __builtin_amdgcn_update_dpp(vi, vi, CTRL, 0xf, 0xf, true);
    return v + __builtin_bit_cast(float, mv);
}

__global__ __launch_bounds__(128)
void scan_kernel(const float* __restrict__ xF,  const float* __restrict__ dtF,
                 const float* __restrict__ xdF, const float* __restrict__ xzF,
                 const float* __restrict__ AlF, const float* __restrict__ DFp,
                 const float* __restrict__ xB,  const float* __restrict__ dtB,
                 const float* __restrict__ xdB, const float* __restrict__ xzB,
                 const float* __restrict__ AlB, const float* __restrict__ DBp,
                 float* __restrict__ ycat)
{
    const int br = blockIdx.z;
    const int bb = blockIdx.y;
    const int d0 = blockIdx.x * 8;

    const float* x    = br ? xB  : xF;
    const float* dt   = br ? dtB : dtF;
    const float* xd   = br ? xdB : xdF;
    const float* xz   = br ? xzB : xzF;
    const float* Alog = br ? AlB : AlF;
    const float* Dp   = br ? DBp : DFp;

    __shared__ float xs [2][SCH][8];
    __shared__ float dts[2][SCH][8];
    __shared__ float zs [2][SCH][8];
    __shared__ float Bss[2][SCH][16];
    __shared__ float Css[2][SCH][16];

    const int t = threadIdx.x;
    const int n = t & 15, dloc = t >> 4;

    const float* xg  = x  + (size_t)bb * Lv * D_INNER + d0;
    const float* dtg = dt + (size_t)bb * Lv * D_INNER + d0;
    const float* zg  = xz + (size_t)bb * Lv * (2*D_INNER) + D_INNER + d0;
    const float* bcg = xd + (size_t)bb * Lv * 128;

    const int sli = t >> 1, sdq = (t & 1) * 4;
    const int bl0 = t >> 2,         bq0 = (t & 3) * 4;
    const int bl1 = (t + 128) >> 2, bq1 = ((t + 128) & 3) * 4;

    #define STAGE(c, p) do {                                                      \
        int l0_ = (c) * SCH;                                                      \
        gll16(xg  + (size_t)(l0_ + sli) * D_INNER     + sdq, &xs [p][sli][sdq]);  \
        gll16(dtg + (size_t)(l0_ + sli) * D_INNER     + sdq, &dts[p][sli][sdq]);  \
        gll16(zg  + (size_t)(l0_ + sli) * (2*D_INNER) + sdq, &zs [p][sli][sdq]);  \
        gll16(bcg + (size_t)(l0_ + bl0) * 128 + DT_RANK           + bq0, &Bss[p][bl0][bq0]); \
        gll16(bcg + (size_t)(l0_ + bl1) * 128 + DT_RANK           + bq1, &Bss[p][bl1][bq1]); \
        gll16(bcg + (size_t)(l0_ + bl0) * 128 + DT_RANK + N_STATE + bq0, &Css[p][bl0][bq0]); \
        gll16(bcg + (size_t)(l0_ + bl1) * 128 + DT_RANK + N_STATE + bq1, &Css[p][bl1][bq1]); \
    } while (0)

    const float An = -__expf(Alog[(d0 + dloc) * N_STATE + n]);
    const float Dd = Dp[d0 + dloc];
    float h = 0.f;

    STAGE(0, 0);
    __syncthreads();

    for (int c = 0; c < SNC; ++c) {
        const int p = c & 1;
        if (c + 1 < SNC) STAGE(c + 1, p ^ 1);

        float yq[4];
        #pragma unroll
        for (int q = 0; q < 4; ++q) {
            float yv = 0.f;
            #pragma unroll
            for (int li = 0; li < 16; ++li) {
                const int l = q * 16 + li;
                float dtl  = dts[p][l][dloc];
                float xl   = xs [p][l][dloc];
                float bsel = Bss[p][l][n];
                float csel = Css[p][l][n];
                float ab = __expf(dtl * An);
                h = fmaf(ab, h, dtl * xl * bsel);
                float contrib = h * csel;
                contrib = dpp_ror_add<0x121>(contrib);  // ror 1
                contrib = dpp_ror_add<0x122>(contrib);  // ror 2
                contrib = dpp_ror_add<0x124>(contrib);  // ror 4
                contrib = dpp_ror_add<0x128>(contrib);  // ror 8
                float zl = zs[p][l][dloc];
                float y = (contrib + xl * Dd) * (zl / (1.f + __expf(-zl)));
                if (li == n) yv = y;
            }
            yq[q] = yv;
        }
        #pragma unroll
        for (int q = 0; q < 4; ++q) {
            int gl = c * SCH + q * 16 + n;
            int lo = br ? (Lv - 1 - gl) : gl;
            ycat[((size_t)bb * Lv + lo) * (2*D_INNER) + br * D_INNER + d0 + dloc] = yq[q];
        }
        __syncthreads();
    }
    #undef STAGE
}

extern "C" void kernel_launch(void* const* d_in, const int* in_sizes, int n_in,
                              void* d_out, int out_size, void* d_ws, size_t ws_size,
                              hipStream_t stream)
{
    (void)in_sizes; (void)n_in; (void)out_size; (void)ws_size;
    const float* u        = (const float*)d_in[0];
    const float* norm_w   = (const float*)d_in[1];
    const float* norm_b   = (const float*)d_in[2];
    const float* f_in_w   = (const float*)d_in[3];
    const float* f_conv_w = (const float*)d_in[4];
    const float* f_conv_b = (const float*)d_in[5];
    const float* f_Alog   = (const float*)d_in[6];
    const float* f_xproj  = (const float*)d_in[7];
    const float* f_dt_w   = (const float*)d_in[8];
    const float* f_dt_b   = (const float*)d_in[9];
    const float* f_D      = (const float*)d_in[10];
    const float* b_in_w   = (const float*)d_in[11];
    const float* b_conv_w = (const float*)d_in[12];
    const float* b_conv_b = (const float*)d_in[13];
    const float* b_Alog   = (const float*)d_in[14];
    const float* b_xproj  = (const float*)d_in[15];
    const float* b_dt_w   = (const float*)d_in[16];
    const float* b_dt_b   = (const float*)d_in[17];
    const float* b_D      = (const float*)d_in[18];
    const float* out_w    = (const float*)d_in[19];
    float* out = (float*)d_out;

    float* ws = (float*)d_ws;
    float* un     = ws;                                      // 2048*768
    float* xz_f   = un     + (size_t)MROWS * D_MODEL;        // 2048*3072
    float* xz_b   = xz_f   + (size_t)MROWS * 2 * D_INNER;
    float* x_f    = xz_b   + (size_t)MROWS * 2 * D_INNER;    // 2048*1536
    float* x_b    = x_f    + (size_t)MROWS * D_INNER;
    float* xdbl_f = x_b    + (size_t)MROWS * D_INNER;        // 2048*128
    float* xdbl_b = xdbl_f + (size_t)MROWS * 128;
    float* dt_f   = xdbl_b + (size_t)MROWS * 128;            // 2048*1536
    float* dt_b_  = dt_f   + (size_t)MROWS * D_INNER;
    float* ycat   = dt_b_  + (size_t)MROWS * D_INNER;        // 2048*3072
    float* tail   = ycat   + (size_t)MROWS * 2 * D_INNER;

    // bf16 scratch (aliased onto fp32 buffers that are dead in the relevant window)
    unsigned short* un_bf = (unsigned short*)tail;           // fresh: 2048*768 shorts (3MB)
    unsigned short* fw_bf = (unsigned short*)dt_f;           // dead until dt GEMM writes (step 5)
    unsigned short* bw_bf = (unsigned short*)dt_b_;
    unsigned short* yc_bf = (unsigned short*)x_f;            // x_f dead after scan
    unsigned short* ow_bf = (unsigned short*)x_b;            // x_b dead after scan

    // 1. LayerNorm
    ln_kernel<<<MROWS, 256, 0, stream>>>(u, norm_w, norm_b, un);

    // 2. convert un + in-proj weights to bf16
    f2b<<<(MROWS*D_MODEL/4 + 255)/256, 256, 0, stream>>>(un, un_bf, MROWS*D_MODEL/4);
    f2b<<<(2*D_INNER*D_MODEL/4 + 255)/256, 256, 0, stream>>>(f_in_w, fw_bf, 2*D_INNER*D_MODEL/4);
    f2b<<<(2*D_INNER*D_MODEL/4 + 255)/256, 256, 0, stream>>>(b_in_w, bw_bf, 2*D_INNER*D_MODEL/4);

    // 3. in-proj GEMMs (bf16 MFMA; bwd reads reversed rows)
    gemm_mfma<<<dim3(2*D_INNER/128, MROWS/128), 256, 0, stream>>>(
        un_bf, 0, Lv, fw_bf, nullptr, xz_f, MROWS, 2*D_INNER, D_MODEL);
    gemm_mfma<<<dim3(2*D_INNER/128, MROWS/128), 256, 0, stream>>>(
        un_bf, 1, Lv, bw_bf, nullptr, xz_b, MROWS, 2*D_INNER, D_MODEL);

    // 4. conv + SiLU
    int convBlocks = (Bv * (Lv/8) * D_INNER) / 256;
    conv_silu<<<convBlocks, 256, 0, stream>>>(xz_f, f_conv_w, f_conv_b, x_f);
    conv_silu<<<convBlocks, 256, 0, stream>>>(xz_b, b_conv_w, b_conv_b, x_b);

    // 5. x-proj GEMMs (fp32)
    gemm_bt<<<dim3(128/64, MROWS/64), 256, 0, stream>>>(
        x_f, D_INNER, 0, 0, Lv, f_xproj, D_INNER, nullptr, 0, nullptr, 0,
        xdbl_f, 128, MROWS, 128, D_INNER);
    gemm_bt<<<dim3(128/64, MROWS/64), 256, 0, stream>>>(
        x_b, D_INNER, 0, 0, Lv, b_xproj, D_INNER, nullptr, 0, nullptr, 0,
        xdbl_b, 128, MROWS, 128, D_INNER);

    // 6. dt GEMMs + bias + softplus (fp32; overwrites fw_bf/bw_bf — they're done)
    gemm_bt<<<dim3(D_INNER/64, MROWS/64), 256, 0, stream>>>(
        xdbl_f, 128, 0, 0, Lv, f_dt_w, DT_RANK, f_dt_b, 2, nullptr, 0,
        dt_f, D_INNER, MROWS, D_INNER, DT_RANK);
    gemm_bt<<<dim3(D_INNER/64, MROWS/64), 256, 0, stream>>>(
        xdbl_b, 128, 0, 0, Lv, b_dt_w, DT_RANK, b_dt_b, 2, nullptr, 0,
        dt_b_, D_INNER, MROWS, D_INNER, DT_RANK);

    // 7. selective scan + gate
    scan_kernel<<<dim3(D_INNER/8, Bv, 2), 128, 0, stream>>>(
        x_f, dt_f, xdbl_f, xz_f, f_Alog, f_D,
        x_b, dt_b_, xdbl_b, xz_b, b_Alog, b_D, ycat);

    // 8. convert ycat + out_w to bf16 (into now-dead x_f / x_b)
    f2b<<<(MROWS*2*D_INNER/4 + 255)/256, 256, 0, stream>>>(ycat, yc_bf, MROWS*2*D_INNER/4);
    f2b<<<(D_MODEL*2*D_INNER/4 + 255)/256, 256, 0, stream>>>(out_w, ow_bf, D_MODEL*2*D_INNER/4);

    // 9. out-proj GEMM (bf16 MFMA) + residual
    gemm_mfma<<<dim3(D_MODEL/128, MROWS/128), 256, 0, stream>>>(
        yc_bf, 0, Lv, ow_bf, u, out, MROWS, D_MODEL, 2*D_INNER);
}

// Round 5
// 519.783 us; speedup vs baseline: 3.0821x; 1.3010x over previous
//
#include <hip/hip_runtime.h>
#include <hip/hip_bf16.h>

#define D_MODEL 768
#define D_INNER 1536
#define N_STATE 16
#define DT_RANK 96
#define KCONV   4
#define Bv      2
#define Lv      1024
#define MROWS   (Bv*Lv)   // 2048

typedef __attribute__((ext_vector_type(8))) short bf16x8;
typedef __attribute__((ext_vector_type(4))) float f32x4;

__device__ __forceinline__ void gll16(const void* g, void* l) {
    __builtin_amdgcn_global_load_lds(
        (const __attribute__((address_space(1))) void*)g,
        (__attribute__((address_space(3))) void*)l, 16, 0, 0);
}

__device__ __forceinline__ unsigned short f2bf(float f) {
    unsigned u = __builtin_bit_cast(unsigned, f);
    u += 0x7fffu + ((u >> 16) & 1u);
    return (unsigned short)(u >> 16);
}

// ---------------- LayerNorm -> bf16 ----------------
__global__ __launch_bounds__(256)
void ln_kernel(const float* __restrict__ u, const float* __restrict__ w,
               const float* __restrict__ bvec, unsigned short* __restrict__ o)
{
    int row = blockIdx.x;
    const float* x = u + (size_t)row * D_MODEL;
    int t = threadIdx.x;
    float v0 = x[t], v1 = x[t + 256], v2 = x[t + 512];
    float s  = v0 + v1 + v2;
    float s2 = v0*v0 + v1*v1 + v2*v2;
    for (int off = 32; off; off >>= 1) {
        s  += __shfl_down(s, off);
        s2 += __shfl_down(s2, off);
    }
    __shared__ float rs[4], rs2[4];
    __shared__ float mu_s, rstd_s;
    int wid = t >> 6, lane = t & 63;
    if (lane == 0) { rs[wid] = s; rs2[wid] = s2; }
    __syncthreads();
    if (t == 0) {
        float S  = rs[0] + rs[1] + rs[2] + rs[3];
        float S2 = rs2[0] + rs2[1] + rs2[2] + rs2[3];
        float mu = S / (float)D_MODEL;
        float var = S2 / (float)D_MODEL - mu * mu;
        mu_s = mu;
        rstd_s = rsqrtf(var + 1e-5f);
    }
    __syncthreads();
    float mu = mu_s, r = rstd_s;
    unsigned short* orow = o + (size_t)row * D_MODEL;
    orow[t]       = f2bf((v0 - mu) * r * w[t]       + bvec[t]);
    orow[t + 256] = f2bf((v1 - mu) * r * w[t + 256] + bvec[t + 256]);
    orow[t + 512] = f2bf((v2 - mu) * r * w[t + 512] + bvec[t + 512]);
}

// ---------------- fp32 -> bf16 bulk convert ----------------
__global__ __launch_bounds__(256)
void f2b(const float* __restrict__ in, unsigned short* __restrict__ o, int n4)
{
    int i = blockIdx.x * 256 + threadIdx.x;
    if (i < n4) {
        float4 v = ((const float4*)in)[i];
        ushort4 r;
        r.x = f2bf(v.x); r.y = f2bf(v.y); r.z = f2bf(v.z); r.w = f2bf(v.w);
        ((ushort4*)o)[i] = r;
    }
}

// ---------------- bf16 MFMA GEMM: C[M,N](f32) = A[M,K](bf16) * W[N,K]^T(bf16) ----------------
__global__ __launch_bounds__(256)
void gemm_mfma(const unsigned short* __restrict__ A, int revA, int Lr,
               const unsigned short* __restrict__ W,
               const float* __restrict__ res,
               float* __restrict__ C,
               int M, int N, int K)
{
    __shared__ unsigned short As[128 * 32];
    __shared__ unsigned short Bs[128 * 32];
    const int tid = threadIdx.x;
    const int m0 = blockIdx.y * 128, n0 = blockIdx.x * 128;
    const int lane = tid & 63;
    const int w  = tid >> 6;
    const int wr = w >> 1, wc = w & 1;
    const int lm = lane & 15, lk = lane >> 4;

    const int srow = tid >> 2;
    const int skq  = (tid & 3) * 8;
    int arow0 = m0 + srow, arow1 = m0 + srow + 64;
    if (revA) {
        arow0 = (arow0 / Lr) * Lr + (Lr - 1 - arow0 % Lr);
        arow1 = (arow1 / Lr) * Lr + (Lr - 1 - arow1 % Lr);
    }
    const unsigned short* a0 = A + (size_t)arow0 * K + skq;
    const unsigned short* a1 = A + (size_t)arow1 * K + skq;
    const unsigned short* w0 = W + (size_t)(n0 + srow) * K + skq;
    const unsigned short* w1 = W + (size_t)(n0 + srow + 64) * K + skq;

    f32x4 acc[4][4] = {};

    for (int k0 = 0; k0 < K; k0 += 32) {
        __syncthreads();
        gll16(a0 + k0, &As[tid * 8]);
        gll16(a1 + k0, &As[2048 + tid * 8]);
        gll16(w0 + k0, &Bs[tid * 8]);
        gll16(w1 + k0, &Bs[2048 + tid * 8]);
        __syncthreads();

        bf16x8 af[4], bfr[4];
        #pragma unroll
        for (int i = 0; i < 4; i++) {
            af[i]  = *(const bf16x8*)&As[(wr * 64 + i * 16 + lm) * 32 + lk * 8];
            bfr[i] = *(const bf16x8*)&Bs[(wc * 64 + i * 16 + lm) * 32 + lk * 8];
        }
        #pragma unroll
        for (int i = 0; i < 4; i++)
            #pragma unroll
            for (int j = 0; j < 4; j++)
                acc[i][j] = __builtin_amdgcn_mfma_f32_16x16x32_bf16(af[i], bfr[j], acc[i][j], 0, 0, 0);
    }

    #pragma unroll
    for (int i = 0; i < 4; i++) {
        #pragma unroll
        for (int j = 0; j < 4; j++) {
            int row = m0 + wr * 64 + i * 16 + lk * 4;
            int col = n0 + wc * 64 + j * 16 + lm;
            #pragma unroll
            for (int r = 0; r < 4; r++) {
                float v = acc[i][j][r];
                if (res) v += res[(size_t)(row + r) * N + col];
                C[(size_t)(row + r) * N + col] = v;
            }
        }
    }
}

// ---------------- Causal depthwise conv (K=4) + SiLU; dual fp32+bf16 out ----------------
__global__ __launch_bounds__(256)
void conv_silu(const float* __restrict__ xz, const float* __restrict__ w,
               const float* __restrict__ bias, float* __restrict__ xo,
               unsigned short* __restrict__ xbf)
{
    int t  = blockIdx.x * 256 + threadIdx.x;
    int d  = t % D_INNER;
    int lc = (t / D_INNER) % (Lv / 8);
    int b  = t / (D_INNER * (Lv / 8));
    int l0 = lc * 8;
    const float* src = xz + (size_t)b * Lv * (2 * D_INNER) + d;
    float w0 = w[d*4], w1 = w[d*4+1], w2 = w[d*4+2], w3 = w[d*4+3];
    float bb = bias[d];
    float v[11];
    #pragma unroll
    for (int j = 0; j < 11; j++) {
        int l = l0 - 3 + j;
        v[j] = (l >= 0) ? src[(size_t)l * (2 * D_INNER)] : 0.f;
    }
    size_t base = ((size_t)b * Lv + l0) * D_INNER + d;
    #pragma unroll
    for (int j = 0; j < 8; j++) {
        float a = bb + w0*v[j] + w1*v[j+1] + w2*v[j+2] + w3*v[j+3];
        a = a / (1.f + __expf(-a));  // SiLU
        xo[base + (size_t)j * D_INNER] = a;
        xbf[base + (size_t)j * D_INNER] = f2bf(a);
    }
}

// ---------------- fp32 GEMM (kept for dt) ----------------
__global__ __launch_bounds__(256)
void gemm_bt(const float* __restrict__ A, int lda, int aoff, int revA, int Lr,
             const float* __restrict__ W, int ldw,
             const float* __restrict__ bias, int act,
             const float* __restrict__ res, int ldres,
             float* __restrict__ C, int ldc,
             int M, int N, int K)
{
    __shared__ float As[16][64];
    __shared__ float Ws[16][64];
    const int t  = threadIdx.x;
    const int m0 = blockIdx.y * 64, n0 = blockIdx.x * 64;
    const int lr = t >> 2, kq = t & 3;
    int am = m0 + lr;
    if (revA) { int b = am / Lr, l = am % Lr; am = b * Lr + (Lr - 1 - l); }
    const float* Ap = A + (size_t)am * lda + aoff + kq * 4;
    const float* Wp = W + (size_t)(n0 + lr) * ldw + kq * 4;
    const int ty = t >> 4, tx = t & 15;
    float acc[4][4] = {};
    for (int k0 = 0; k0 < K; k0 += 16) {
        float4 av = *(const float4*)(Ap + k0);
        float4 wv = *(const float4*)(Wp + k0);
        __syncthreads();
        As[kq*4+0][lr] = av.x; As[kq*4+1][lr] = av.y;
        As[kq*4+2][lr] = av.z; As[kq*4+3][lr] = av.w;
        Ws[kq*4+0][lr] = wv.x; Ws[kq*4+1][lr] = wv.y;
        Ws[kq*4+2][lr] = wv.z; Ws[kq*4+3][lr] = wv.w;
        __syncthreads();
        #pragma unroll
        for (int k = 0; k < 16; k++) {
            float4 ra = *(const float4*)&As[k][ty << 2];
            float4 rw = *(const float4*)&Ws[k][tx << 2];
            float a4[4] = {ra.x, ra.y, ra.z, ra.w};
            float w4[4] = {rw.x, rw.y, rw.z, rw.w};
            #pragma unroll
            for (int i = 0; i < 4; i++)
                #pragma unroll
                for (int j = 0; j < 4; j++)
                    acc[i][j] = fmaf(a4[i], w4[j], acc[i][j]);
        }
    }
    #pragma unroll
    for (int i = 0; i < 4; i++) {
        int row = m0 + (ty << 2) + i;
        #pragma unroll
        for (int j = 0; j < 4; j++) {
            int col = n0 + (tx << 2) + j;
            float v = acc[i][j];
            if (bias) v += bias[col];
            if (act == 2) v = (v > 20.f) ? v : log1pf(__expf(v));
            if (res)  v += res[(size_t)row * ldres + col];
            C[(size_t)row * ldc + col] = v;
        }
    }
}

// ---------------- Selective scan + gate (transposed LDS, b128 reads, DPP reduce) ----------------
#define SCH  64
#define SNC  (Lv/SCH)
#define PADL 68   // padded row stride (68%32==4 -> rows spread across banks)

template<int CTRL>
__device__ __forceinline__ float dpp_ror_add(float v) {
    int vi = __builtin_bit_cast(int, v);
    int mv = __builtin_amdgcn_update_dpp(vi, vi, CTRL, 0xf, 0xf, true);
    return v + __builtin_bit_cast(float, mv);
}

__global__ __launch_bounds__(128)
void scan_kernel(const float* __restrict__ xF,  const float* __restrict__ dtF,
                 const float* __restrict__ xdF, const float* __restrict__ xzF,
                 const float* __restrict__ AlF, const float* __restrict__ DFp,
                 const float* __restrict__ xB,  const float* __restrict__ dtB,
                 const float* __restrict__ xdB, const float* __restrict__ xzB,
                 const float* __restrict__ AlB, const float* __restrict__ DBp,
                 unsigned short* __restrict__ ycat)
{
    const int br = blockIdx.z;
    const int bb = blockIdx.y;
    const int d0 = blockIdx.x * 8;

    const float* x    = br ? xB  : xF;
    const float* dt   = br ? dtB : dtF;
    const float* xd   = br ? xdB : xdF;
    const float* xz   = br ? xzB : xzF;
    const float* Alog = br ? AlB : AlF;
    const float* Dp   = br ? DBp : DFp;

    // transposed, padded: [d or n][l]
    __shared__ float xs [2][8][PADL];
    __shared__ float dts[2][8][PADL];
    __shared__ float zs [2][8][PADL];
    __shared__ float Bss[2][16][PADL];
    __shared__ float Css[2][16][PADL];

    const int t = threadIdx.x;
    const int n = t & 15, dloc = t >> 4;

    const float* xg  = x  + (size_t)bb * Lv * D_INNER + d0;
    const float* dtg = dt + (size_t)bb * Lv * D_INNER + d0;
    const float* zg  = xz + (size_t)bb * Lv * (2*D_INNER) + D_INNER + d0;
    const float* bcg = xd + (size_t)bb * Lv * 128;

    // staging map: x/dt/z: l=t>>1 (64 rows), 4 floats at dq=(t&1)*4
    const int sl = t >> 1, sdq = (t & 1) * 4;
    // B/C: 1024 floats = 256 float4; threads cover slots t and t+128
    const int bl0 = t >> 2,         bq0 = (t & 3) * 4;
    const int bl1 = (t + 128) >> 2, bq1 = ((t + 128) & 3) * 4;

    f32x4 rx, rdt, rz, rb0, rb1, rc0, rc1;

    #define LOADG(c) do {                                                        \
        int l0_ = (c) * SCH;                                                     \
        rx  = *(const f32x4*)(xg  + (size_t)(l0_ + sl) * D_INNER     + sdq);     \
        rdt = *(const f32x4*)(dtg + (size_t)(l0_ + sl) * D_INNER     + sdq);     \
        rz  = *(const f32x4*)(zg  + (size_t)(l0_ + sl) * (2*D_INNER) + sdq);     \
        rb0 = *(const f32x4*)(bcg + (size_t)(l0_ + bl0) * 128 + DT_RANK           + bq0); \
        rb1 = *(const f32x4*)(bcg + (size_t)(l0_ + bl1) * 128 + DT_RANK           + bq1); \
        rc0 = *(const f32x4*)(bcg + (size_t)(l0_ + bl0) * 128 + DT_RANK + N_STATE + bq0); \
        rc1 = *(const f32x4*)(bcg + (size_t)(l0_ + bl1) * 128 + DT_RANK + N_STATE + bq1); \
    } while (0)

    #define WRITEL(p) do {                                                       \
        _Pragma("unroll")                                                        \
        for (int j = 0; j < 4; j++) {                                            \
            xs [p][sdq+j][sl] = rx[j];                                           \
            dts[p][sdq+j][sl] = rdt[j];                                          \
            zs [p][sdq+j][sl] = rz[j];                                           \
            Bss[p][bq0+j][bl0] = rb0[j];                                         \
            Bss[p][bq1+j][bl1] = rb1[j];                                         \
            Css[p][bq0+j][bl0] = rc0[j];                                         \
            Css[p][bq1+j][bl1] = rc1[j];                                         \
        }                                                                        \
    } while (0)

    const float An = -__expf(Alog[(d0 + dloc) * N_STATE + n]);
    const float Dd = Dp[d0 + dloc];
    float h = 0.f;

    LOADG(0);
    WRITEL(0);
    __syncthreads();

    for (int c = 0; c < SNC; ++c) {
        const int p = c & 1;
        if (c + 1 < SNC) LOADG(c + 1);

        float yq[4] = {0.f, 0.f, 0.f, 0.f};
        #pragma unroll
        for (int g = 0; g < 16; ++g) {
            f32x4 xv  = *(const f32x4*)&xs [p][dloc][g*4];
            f32x4 dtv = *(const f32x4*)&dts[p][dloc][g*4];
            f32x4 zv  = *(const f32x4*)&zs [p][dloc][g*4];
            f32x4 bv  = *(const f32x4*)&Bss[p][n][g*4];
            f32x4 cv  = *(const f32x4*)&Css[p][n][g*4];
            #pragma unroll
            for (int j = 0; j < 4; ++j) {
                const int l = g * 4 + j;
                float ab = __expf(dtv[j] * An);
                h = fmaf(ab, h, dtv[j] * xv[j] * bv[j]);
                float contrib = h * cv[j];
                contrib = dpp_ror_add<0x121>(contrib);
                contrib = dpp_ror_add<0x122>(contrib);
                contrib = dpp_ror_add<0x124>(contrib);
                contrib = dpp_ror_add<0x128>(contrib);
                float y = (contrib + xv[j] * Dd)
                        * (zv[j] * __builtin_amdgcn_rcpf(1.f + __expf(-zv[j])));
                if ((l & 15) == n) yq[l >> 4] = y;
            }
        }

        if (c + 1 < SNC) WRITEL(p ^ 1);

        #pragma unroll
        for (int q = 0; q < 4; ++q) {
            int gl = c * SCH + q * 16 + n;
            int lo = br ? (Lv - 1 - gl) : gl;
            ycat[((size_t)bb * Lv + lo) * (2*D_INNER) + br * D_INNER + d0 + dloc] = f2bf(yq[q]);
        }
        __syncthreads();
    }
    #undef LOADG
    #undef WRITEL
}

extern "C" void kernel_launch(void* const* d_in, const int* in_sizes, int n_in,
                              void* d_out, int out_size, void* d_ws, size_t ws_size,
                              hipStream_t stream)
{
    (void)in_sizes; (void)n_in; (void)out_size; (void)ws_size;
    const float* u        = (const float*)d_in[0];
    const float* norm_w   = (const float*)d_in[1];
    const float* norm_b   = (const float*)d_in[2];
    const float* f_in_w   = (const float*)d_in[3];
    const float* f_conv_w = (const float*)d_in[4];
    const float* f_conv_b = (const float*)d_in[5];
    const float* f_Alog   = (const float*)d_in[6];
    const float* f_xproj  = (const float*)d_in[7];
    const float* f_dt_w   = (const float*)d_in[8];
    const float* f_dt_b   = (const float*)d_in[9];
    const float* f_D      = (const float*)d_in[10];
    const float* b_in_w   = (const float*)d_in[11];
    const float* b_conv_w = (const float*)d_in[12];
    const float* b_conv_b = (const float*)d_in[13];
    const float* b_Alog   = (const float*)d_in[14];
    const float* b_xproj  = (const float*)d_in[15];
    const float* b_dt_w   = (const float*)d_in[16];
    const float* b_dt_b   = (const float*)d_in[17];
    const float* b_D      = (const float*)d_in[18];
    const float* out_w    = (const float*)d_in[19];
    float* out = (float*)d_out;

    float* ws = (float*)d_ws;
    float* p = ws;
    unsigned short* un_bf = (unsigned short*)p;  p += (size_t)MROWS * D_MODEL;     // bf16 in fp32-sized slot
    float* xz_f   = p;  p += (size_t)MROWS * 2 * D_INNER;
    float* xz_b   = p;  p += (size_t)MROWS * 2 * D_INNER;
    float* x_f    = p;  p += (size_t)MROWS * D_INNER;
    float* x_b    = p;  p += (size_t)MROWS * D_INNER;
    unsigned short* xbf_f = (unsigned short*)p;  p += (size_t)MROWS * D_INNER / 2;
    unsigned short* xbf_b = (unsigned short*)p;  p += (size_t)MROWS * D_INNER / 2;
    float* xdbl_f = p;  p += (size_t)MROWS * 128;
    float* xdbl_b = p;  p += (size_t)MROWS * 128;
    float* dt_f   = p;  p += (size_t)MROWS * D_INNER;
    float* dt_b_  = p;  p += (size_t)MROWS * D_INNER;
    unsigned short* yc_bf = (unsigned short*)p;  p += (size_t)MROWS * D_INNER;     // 2048*3072 bf16
    unsigned short* fw_bf = (unsigned short*)p;  p += (size_t)D_INNER * D_MODEL;   // 3072*768 bf16
    unsigned short* bw_bf = (unsigned short*)p;  p += (size_t)D_INNER * D_MODEL;
    unsigned short* xwf_bf = (unsigned short*)p; p += (size_t)64 * D_INNER;        // 128*1536 bf16
    unsigned short* xwb_bf = (unsigned short*)p; p += (size_t)64 * D_INNER;
    unsigned short* ow_bf = (unsigned short*)p;  p += (size_t)D_MODEL * D_INNER;   // 768*3072 bf16

    // 1. LayerNorm -> bf16
    ln_kernel<<<MROWS, 256, 0, stream>>>(u, norm_w, norm_b, un_bf);

    // 2. weight conversions to bf16
    f2b<<<(2*D_INNER*D_MODEL/4 + 255)/256, 256, 0, stream>>>(f_in_w, fw_bf, 2*D_INNER*D_MODEL/4);
    f2b<<<(2*D_INNER*D_MODEL/4 + 255)/256, 256, 0, stream>>>(b_in_w, bw_bf, 2*D_INNER*D_MODEL/4);
    f2b<<<(128*D_INNER/4 + 255)/256, 256, 0, stream>>>(f_xproj, xwf_bf, 128*D_INNER/4);
    f2b<<<(128*D_INNER/4 + 255)/256, 256, 0, stream>>>(b_xproj, xwb_bf, 128*D_INNER/4);
    f2b<<<(D_MODEL*2*D_INNER/4 + 255)/256, 256, 0, stream>>>(out_w, ow_bf, D_MODEL*2*D_INNER/4);

    // 3. in-proj GEMMs (bf16 MFMA; bwd reads reversed rows)
    gemm_mfma<<<dim3(2*D_INNER/128, MROWS/128), 256, 0, stream>>>(
        un_bf, 0, Lv, fw_bf, nullptr, xz_f, MROWS, 2*D_INNER, D_MODEL);
    gemm_mfma<<<dim3(2*D_INNER/128, MROWS/128), 256, 0, stream>>>(
        un_bf, 1, Lv, bw_bf, nullptr, xz_b, MROWS, 2*D_INNER, D_MODEL);

    // 4. conv + SiLU (dual fp32 + bf16 outputs)
    int convBlocks = (Bv * (Lv/8) * D_INNER) / 256;
    conv_silu<<<convBlocks, 256, 0, stream>>>(xz_f, f_conv_w, f_conv_b, x_f, xbf_f);
    conv_silu<<<convBlocks, 256, 0, stream>>>(xz_b, b_conv_w, b_conv_b, x_b, xbf_b);

    // 5. x-proj GEMMs (bf16 MFMA, N=128)
    gemm_mfma<<<dim3(1, MROWS/128), 256, 0, stream>>>(
        xbf_f, 0, Lv, xwf_bf, nullptr, xdbl_f, MROWS, 128, D_INNER);
    gemm_mfma<<<dim3(1, MROWS/128), 256, 0, stream>>>(
        xbf_b, 0, Lv, xwb_bf, nullptr, xdbl_b, MROWS, 128, D_INNER);

    // 6. dt GEMMs + bias + softplus (fp32)
    gemm_bt<<<dim3(D_INNER/64, MROWS/64), 256, 0, stream>>>(
        xdbl_f, 128, 0, 0, Lv, f_dt_w, DT_RANK, f_dt_b, 2, nullptr, 0,
        dt_f, D_INNER, MROWS, D_INNER, DT_RANK);
    gemm_bt<<<dim3(D_INNER/64, MROWS/64), 256, 0, stream>>>(
        xdbl_b, 128, 0, 0, Lv, b_dt_w, DT_RANK, b_dt_b, 2, nullptr, 0,
        dt_b_, D_INNER, MROWS, D_INNER, DT_RANK);

    // 7. selective scan + gate -> bf16 ycat
    scan_kernel<<<dim3(D_INNER/8, Bv, 2), 128, 0, stream>>>(
        x_f, dt_f, xdbl_f, xz_f, f_Alog, f_D,
        x_b, dt_b_, xdbl_b, xz_b, b_Alog, b_D, yc_bf);

    // 8. out-proj GEMM (bf16 MFMA) + residual
    gemm_mfma<<<dim3(D_MODEL/128, MROWS/128), 256, 0, stream>>>(
        yc_bf, 0, Lv, ow_bf, u, out, MROWS, D_MODEL, 2*D_INNER);
}